// Round 2
// 228.682 us; speedup vs baseline: 1.0146x; 1.0146x over previous
//
#include <hip/hip_runtime.h>

// Problem: B=8, C=256, T=16, H=28, W=28
//   h_t = 0.5*(W @ h_{t-1} + x_t)   (channel matmul per spatial position)
//   out[:,:,0] = x0; out[:,:,t] = h_t
//
// Strategy: 392 blocks of 16 spatial columns; h round-trips through
// double-buffered bf16 LDS, W preloaded as MFMA A-fragments.
// x_t is prefetched one full step ahead into a double-buffered LDS slab via
// global_load_lds (fire-and-forget, 16B/lane), issued right after each step's
// barrier and drained by the NEXT barrier's implicit vmcnt(0). This removes
// the per-step serial HBM-latency stall on the 16 scalar x loads that
// dominated the 232us version (latency-bound: 2.1 TB/s at 26% peak).

typedef __attribute__((ext_vector_type(8))) short bf16x8;  // 8 bf16 = 4 VGPRs
typedef __attribute__((ext_vector_type(4))) float f32x4;
typedef __attribute__((ext_vector_type(4))) short short4v;

#define NTILES 49       // 784 / 16 spatial tiles per batch
#define LDSK   264      // 256 + 8 bf16 pad -> stride 528 B

// async global->LDS, 16B per lane; LDS dest is wave-uniform base + lane*16
#define ASYNC16(gsrc, ldst)                                                    \
    __builtin_amdgcn_global_load_lds(                                          \
        (const __attribute__((address_space(1))) void*)(gsrc),                 \
        (__attribute__((address_space(3))) void*)(ldst), 16, 0, 0)

__device__ __forceinline__ short f2bf(float f) {
    // round-to-nearest-even fp32 -> bf16 (inputs finite)
    union { float f; unsigned u; } v; v.f = f;
    unsigned r = v.u + 0x7FFFu + ((v.u >> 16) & 1u);
    return (short)(r >> 16);
}

__global__ __launch_bounds__(256, 2)
void rcu_kernel(const float* __restrict__ in, const float* __restrict__ Wm,
                float* __restrict__ out) {
    // h double-buffer, bf16 [n=16][k=256(+8)] : 16896 B
    __shared__ short hbuf[2][16][LDSK];
    // x double-buffer, fp32 [c=256][s=16] : 32768 B (linear, matches
    // global_load_lds lane order: lane l of issue (w,i) -> chan (w*4+i)*16 + l/4,
    // spatial quad l%4)
    __shared__ float xlds[2][256][16];

    const int tid  = threadIdx.x;
    const int wave = tid >> 6;      // 4 waves: wave w owns channels [w*64, w*64+64)
    const int lane = tid & 63;
    const int l15  = lane & 15;
    const int quad = lane >> 4;

    const int b  = blockIdx.x / NTILES;
    const int s0 = (blockIdx.x % NTILES) * 16;

    // Flat index: ((b*256 + c)*16 + t)*784 + s ;  c-stride = 12544 floats
    const size_t base = (size_t)b * 256 * 16 * 784 + s0;
    const float* xin  = in  + base;
    float*       xout = out + base;

    // per-lane source decomposition for the async copies
    const int cidx = lane >> 2;         // channel within a 16-channel chunk
    const int sq   = (lane & 3) * 4;    // spatial float4 within the 16-col tile

    // ---- issue x(t=0) prefetch into xlds[0] (needed first) ----
#pragma unroll
    for (int i = 0; i < 4; ++i) {
        const int cbi = (wave * 4 + i) * 16;
        ASYNC16(xin + (size_t)(cbi + cidx) * 12544 + sq, &xlds[0][cbi][0]);
    }

    // ---- Preload W as bf16 A-fragments (once; reused for all 15 steps) ----
    // A[m][k]: m = lane&15 (+tile base), k = quad*8 + j
    bf16x8 a_frag[4][8];            // 4 m-tiles x 8 k-steps = 128 regs
#pragma unroll
    for (int mt = 0; mt < 4; ++mt) {
        const int m = wave * 64 + mt * 16 + l15;
        const float* wrow = Wm + m * 256 + quad * 8;
#pragma unroll
        for (int ks = 0; ks < 8; ++ks) {
            float4 f0 = *(const float4*)(wrow + ks * 32);
            float4 f1 = *(const float4*)(wrow + ks * 32 + 4);
            bf16x8 a;
            a[0] = f2bf(f0.x); a[1] = f2bf(f0.y); a[2] = f2bf(f0.z); a[3] = f2bf(f0.w);
            a[4] = f2bf(f1.x); a[5] = f2bf(f1.y); a[6] = f2bf(f1.z); a[7] = f2bf(f1.w);
            a_frag[mt][ks] = a;
        }
    }

    // ---- issue x(t=1) prefetch into xlds[1] ----
#pragma unroll
    for (int i = 0; i < 4; ++i) {
        const int cbi = (wave * 4 + i) * 16;
        ASYNC16(xin + (size_t)(cbi + cidx) * 12544 + 784 + sq, &xlds[1][cbi][0]);
    }

    __syncthreads();   // implicit vmcnt(0): x(0), x(1) landed; xlds published

    // ---- Init from xlds[0]: out(t=0) passthrough + stage h0 into hbuf[0] ----
    {
        const int sg = tid & 15;      // spatial within tile
        const int cg = tid >> 4;      // channel group 0..15
#pragma unroll
        for (int i = 0; i < 16; ++i) {
            const int c = cg * 16 + i;
            const float v = xlds[0][c][sg];
            xout[(size_t)c * 12544 + sg] = v;       // t = 0
            hbuf[0][sg][c] = f2bf(v);
        }
    }
    __syncthreads();

    int cur = 0;
    for (int t = 1; t < 16; ++t) {
        const int xb = t & 1;        // xlds buffer holding x(t)

        // ---- prefetch x(t+1) into the other x buffer (drained at the
        //      barrier at the END of this step -> one full step of overlap)
        if (t < 15) {
#pragma unroll
            for (int i = 0; i < 4; ++i) {
                const int cbi = (wave * 4 + i) * 16;
                ASYNC16(xin + (size_t)(cbi + cidx) * 12544 + (size_t)(t + 1) * 784 + sq,
                        &xlds[xb ^ 1][cbi][0]);
            }
        }

        // B fragments from LDS: B[k][n], k = ks*32 + quad*8 + j, n = lane&15
        bf16x8 bfrag[8];
        const short* hp = &hbuf[cur][l15][quad * 8];
#pragma unroll
        for (int ks = 0; ks < 8; ++ks)
            bfrag[ks] = *(const bf16x8*)(hp + ks * 32);   // ds_read_b128

        const int nxt = cur ^ 1;
#pragma unroll
        for (int mt = 0; mt < 4; ++mt) {
            f32x4 acc = {0.f, 0.f, 0.f, 0.f};
#pragma unroll
            for (int ks = 0; ks < 8; ++ks)
                acc = __builtin_amdgcn_mfma_f32_16x16x32_bf16(a_frag[mt][ks], bfrag[ks], acc, 0, 0, 0);

            // D layout: row(channel within tile) = quad*4 + r, col(spatial) = lane&15
            const int c0 = wave * 64 + mt * 16 + quad * 4;
            short4v hbf;
#pragma unroll
            for (int r = 0; r < 4; ++r) {
                const float xv = xlds[xb][c0 + r][l15];            // LDS, not HBM
                const float v  = 0.5f * (acc[r] + xv);
                xout[((size_t)(c0 + r) * 16 + t) * 784 + l15] = v;
                hbf[r] = f2bf(v);
            }
            // 4 consecutive channels -> one 8B LDS write
            *(short4v*)&hbuf[nxt][l15][c0] = hbf;
        }
        __syncthreads();   // publishes hbuf[nxt] AND drains x(t+1) prefetch
        cur = nxt;
    }
}

extern "C" void kernel_launch(void* const* d_in, const int* in_sizes, int n_in,
                              void* d_out, int out_size, void* d_ws, size_t ws_size,
                              hipStream_t stream) {
    const float* in  = (const float*)d_in[0];
    const float* Wm  = (const float*)d_in[1];
    float*       out = (float*)d_out;
    hipLaunchKernelGGL(rcu_kernel, dim3(8 * NTILES), dim3(256), 0, stream, in, Wm, out);
}